// Round 16
// baseline (125.766 us; speedup 1.0000x reference)
//
#include <hip/hip_runtime.h>
#include <hip/hip_bf16.h>

typedef __bf16 bf16x8 __attribute__((ext_vector_type(8)));
typedef float  f32x4  __attribute__((ext_vector_type(4)));

#define NEGC (-10000.0f)

static __device__ __forceinline__ void glds16(const __bf16* src, __bf16* dst) {
    __builtin_amdgcn_global_load_lds((const __attribute__((address_space(1))) unsigned int*)src,
                                     (__attribute__((address_space(3))) unsigned int*)dst, 16, 0, 0);
}

// ---------------------------------------------------------------- fused f32->bf16 convert
__global__ __launch_bounds__(256) void cvt_all(
    const float* __restrict__ emb, const float* __restrict__ wq, const float* __restrict__ wk,
    const float* __restrict__ wv, const float* __restrict__ wo,
    __bf16* __restrict__ Xb, __bf16* __restrict__ Wall)
{
    int blk = blockIdx.x;
    const float* src; __bf16* dst; int i;
    if (blk < 1536) {
        src = emb; dst = Xb; i = blk * 256 + threadIdx.x;
    } else {
        int b2 = blk - 1536;
        int which = b2 / 288;
        src = which == 0 ? wq : which == 1 ? wk : which == 2 ? wv : wo;
        dst = Wall + (size_t)which * 589824;
        i = (b2 - which * 288) * 256 + threadIdx.x;
    }
    f32x4 a = *(const f32x4*)(src + (size_t)i * 8);
    f32x4 b = *(const f32x4*)(src + (size_t)i * 8 + 4);
    bf16x8 o;
    o[0] = (__bf16)a[0]; o[1] = (__bf16)a[1]; o[2] = (__bf16)a[2]; o[3] = (__bf16)a[3];
    o[4] = (__bf16)b[0]; o[5] = (__bf16)b[1]; o[6] = (__bf16)b[2]; o[7] = (__bf16)b[3];
    *(bf16x8*)(dst + (size_t)i * 8) = o;
}

// ---------------------------------------------------------------- GEMM (R14: BK=64 + XOR swizzle, XCD grid)
template<int MODE>
__global__ __launch_bounds__(256) void gemm128(
    const __bf16* __restrict__ A, const __bf16* __restrict__ Bw,
    const float* __restrict__ b0, const float* __restrict__ b1, const float* __restrict__ b2,
    __bf16* __restrict__ O0, __bf16* __restrict__ O1, __bf16* __restrict__ O2,
    const float* __restrict__ res, float* __restrict__ Yout)
{
    __shared__ __align__(16) __bf16 As[128 * 64];
    __shared__ __align__(16) __bf16 Bs[128 * 64];
    const int K = 768;
    const int NT = (MODE == 0) ? 18 : 6;
    int wgid = blockIdx.x;
    int xcd = wgid & 7;
    int t = wgid >> 3;
    int m0 = (xcd * 4 + t / NT) * 128;
    int n0 = (t % NT) * 128;

    int tid = threadIdx.x;
    int l = tid & 63, w = tid >> 6;
    int lo = l & 15, hi = l >> 4;
    int wr = w >> 1, wc = w & 1;

    f32x4 acc[4][4] = {};

    int srow = tid >> 3;
    int scb  = (tid & 7) ^ (srow & 7);
    const __bf16* gA = A + (size_t)(m0 + srow) * K + scb * 8;
    const __bf16* gB = Bw + (size_t)(n0 + srow) * K + scb * 8;
    __bf16* lA = As + tid * 8;
    __bf16* lB = Bs + tid * 8;

    for (int k0 = 0; k0 < K; k0 += 64) {
        if (k0) __syncthreads();
#pragma unroll
        for (int p = 0; p < 4; p++) {
            glds16(gA + (size_t)p * 32 * K + k0, lA + p * 2048);
            glds16(gB + (size_t)p * 32 * K + k0, lB + p * 2048);
        }
        __syncthreads();

#pragma unroll
        for (int kk = 0; kk < 2; kk++) {
            bf16x8 af[4], bfr[4];
#pragma unroll
            for (int mi = 0; mi < 4; mi++)
                af[mi] = *(const bf16x8*)(As + (wr * 64 + mi * 16 + lo) * 64 + (((kk * 4 + hi) ^ (lo & 7)) * 8));
#pragma unroll
            for (int ni = 0; ni < 4; ni++)
                bfr[ni] = *(const bf16x8*)(Bs + (wc * 64 + ni * 16 + lo) * 64 + (((kk * 4 + hi) ^ (lo & 7)) * 8));
#pragma unroll
            for (int mi = 0; mi < 4; mi++)
#pragma unroll
                for (int ni = 0; ni < 4; ni++)
                    acc[mi][ni] = __builtin_amdgcn_mfma_f32_16x16x32_bf16(af[mi], bfr[ni], acc[mi][ni], 0, 0, 0);
        }
    }

    if constexpr (MODE == 0) {
        int which = n0 / 768;
        const float* bias = which == 0 ? b0 : (which == 1 ? b1 : b2);
        __bf16* O = which == 0 ? O0 : (which == 1 ? O1 : O2);
        int nbase = n0 - which * 768;
#pragma unroll
        for (int mi = 0; mi < 4; mi++)
#pragma unroll
            for (int ni = 0; ni < 4; ni++) {
                int within = nbase + wc * 64 + ni * 16 + lo;
                float bv = bias[within];
                int h = within >> 6, d = within & 63;
#pragma unroll
                for (int i = 0; i < 4; i++) {
                    int m = m0 + wr * 64 + mi * 16 + hi * 4 + i;
                    int bb = m >> 10, s = m & 1023;
                    O[(size_t)((bb * 12 + h) * 1024 + s) * 64 + d] = (__bf16)(acc[mi][ni][i] + bv);
                }
            }
    } else {
#pragma unroll
        for (int mi = 0; mi < 4; mi++)
#pragma unroll
            for (int ni = 0; ni < 4; ni++) {
                int n = n0 + wc * 64 + ni * 16 + lo;
                float bv = b0[n];
#pragma unroll
                for (int i = 0; i < 4; i++) {
                    int m = m0 + wr * 64 + mi * 16 + hi * 4 + i;
                    size_t idx = (size_t)m * 768 + n;
                    Yout[idx] = acc[mi][ni][i] + bv + res[idx];
                }
            }
    }
}

// ---------------------------------------------------------------- attention: QBLK=128, 512 threads / 8 waves
// Same per-wave inner loop as R15 (16 q-rows/wave); per staged 64-key tile
// now serves 128 q-rows -> tile-phases per head-pass 136 -> 72, staging and
// barriers per unit work halved. Counted-vmcnt phase sync (1 glds/thread:
// pass1 vmcnt(1)/(0); pass2 vmcnt(16)). LDS 52 KB, 2 blocks x 8 waves /CU.
__global__ __launch_bounds__(512) void attn_kernel(
    const __bf16* __restrict__ Q, const __bf16* __restrict__ K, const __bf16* __restrict__ V,
    const float* __restrict__ pmask, float* __restrict__ Pout, __bf16* __restrict__ ctx)
{
    int wgid = blockIdx.x;
    int xcd = wgid & 7;
    int t = wgid >> 3;              // 0..47
    int bh = xcd * 6 + (t % 6);     // 6 heads per XCD
    int y = t / 6;                  // 0..7  (128-row q-block)
    int KTB = 2 * y + 1;            // last 64-key tile index
    int b = bh / 12, h = bh - b * 12;
    int q0 = y * 128;
    int tid = threadIdx.x, l = tid & 63, w = tid >> 6;   // w in 0..7
    int lo = l & 15, hi = l >> 4;
    int qw = q0 + w * 16;

    const __bf16* Qh = Q + (size_t)bh * 65536;
    const __bf16* Kh = K + (size_t)bh * 65536;
    const __bf16* Vh = V + (size_t)bh * 65536;
    float* Ph = Pout + (size_t)bh * 1048576;
    const float* pm = pmask + b * 1024;

    __shared__ __align__(16) __bf16 Ks[2][64][64];    // 16 KB, dbuf, XOR-swizzled cols
    __shared__ __align__(16) __bf16 vt[2][64][72];    // 18 KB, V^T [d][key], dbuf
    __shared__ __align__(16) __bf16 plds[8][16][72];  // 18 KB, per-wave P tile

    const float scale = 0.036084391824351615f;  // 1/sqrt(768)

    bf16x8 qf0 = *(const bf16x8*)(Qh + (size_t)(qw + lo) * 64 + hi * 8);
    bf16x8 qf1 = *(const bf16x8*)(Qh + (size_t)(qw + lo) * 64 + 32 + hi * 8);

    // K staging: 512 threads, 1 glds each covers the 64x64 tile
    int srow = tid >> 3;                 // 0..63
    int scb  = (tid & 7) ^ (srow & 7);   // XOR-swizzled source colblock
    __bf16* ldst0 = &Ks[0][0][0] + tid * 8;

#define STAGE_K(buf, kt) \
    glds16(Kh + (size_t)((kt) * 64 + srow) * 64 + scb * 8, ldst0 + (buf) * 4096)

#define KFRAG(buf, kn, dh) \
    (*(const bf16x8*)(&Ks[buf][(kn) * 16 + lo][(((dh) * 4 + hi) ^ (lo & 7)) * 8]))

#define WAITV(n)  asm volatile("s_waitcnt vmcnt(" #n ")" ::: "memory")
#define WAITL     asm volatile("s_waitcnt lgkmcnt(0)" ::: "memory")
#define BAR       __builtin_amdgcn_s_barrier()

    // ---------------- pass 1: row sums; counted-vmcnt phase sync
    float lsum[4] = {};
    STAGE_K(0, 0);
    for (int kt = 0; kt <= KTB; kt++) {
        int cur = kt & 1;
        if (kt < KTB) { STAGE_K(cur ^ 1, kt + 1); WAITV(1); }
        else          { WAITV(0); }
        BAR;
        int k0 = kt * 64;
        float pad[4];
#pragma unroll
        for (int kn = 0; kn < 4; kn++) pad[kn] = (1.0f - pm[k0 + kn * 16 + lo]) * NEGC;
        f32x4 s[4] = {};
        __builtin_amdgcn_s_setprio(1);
#pragma unroll
        for (int kn = 0; kn < 4; kn++) {
            s[kn] = __builtin_amdgcn_mfma_f32_16x16x32_bf16(qf0, KFRAG(cur, kn, 0), s[kn], 0, 0, 0);
            s[kn] = __builtin_amdgcn_mfma_f32_16x16x32_bf16(qf1, KFRAG(cur, kn, 1), s[kn], 0, 0, 0);
        }
        __builtin_amdgcn_s_setprio(0);
#pragma unroll
        for (int kn = 0; kn < 4; kn++) {
            int c = k0 + kn * 16 + lo;
#pragma unroll
            for (int i = 0; i < 4; i++) {
                int r = qw + hi * 4 + i;
                float a = s[kn][i] * scale + pad[kn];
                if (c > r) a = NEGC;
                lsum[i] += __expf(a);
            }
        }
        WAITL; BAR;
    }

    float invl[4];
#pragma unroll
    for (int i = 0; i < 4; i++) {
        float s = lsum[i];
        s += __shfl_xor(s, 1);
        s += __shfl_xor(s, 2);
        s += __shfl_xor(s, 4);
        s += __shfl_xor(s, 8);
        invl[i] = 1.0f / s;
    }

    // ---------------- pass 2: QK recompute, P store, PV; vmcnt(16) phase sync
    int vrow = tid >> 3, vcol = (tid & 7) * 8;   // 512 threads: one bf16x8 each
    bf16x8 va;
    {   // prologue: K0 + V0 staged, V1 prefetched (KTB >= 1 always)
        STAGE_K(0, 0);
        const __bf16* vp = Vh + (size_t)vrow * 64 + vcol;
        bf16x8 v0 = *(const bf16x8*)vp;
#pragma unroll
        for (int j = 0; j < 8; j++) vt[0][vcol + j][vrow] = v0[j];
        va = *(const bf16x8*)(Vh + (size_t)(64 + vrow) * 64 + vcol);
        __syncthreads();
    }

    f32x4 cacc[4] = {};
    for (int kt = 0; kt <= KTB; kt++) {
        int cur = kt & 1;
        if (kt < KTB) STAGE_K(cur ^ 1, kt + 1);
        WAITV(16);
        BAR;
        int k0 = kt * 64;
        float pad[4];
#pragma unroll
        for (int kn = 0; kn < 4; kn++) pad[kn] = (1.0f - pm[k0 + kn * 16 + lo]) * NEGC;
        f32x4 s[4] = {};
        __builtin_amdgcn_s_setprio(1);
#pragma unroll
        for (int kn = 0; kn < 4; kn++) {
            s[kn] = __builtin_amdgcn_mfma_f32_16x16x32_bf16(qf0, KFRAG(cur, kn, 0), s[kn], 0, 0, 0);
            s[kn] = __builtin_amdgcn_mfma_f32_16x16x32_bf16(qf1, KFRAG(cur, kn, 1), s[kn], 0, 0, 0);
        }
        __builtin_amdgcn_s_setprio(0);
#pragma unroll
        for (int kn = 0; kn < 4; kn++) {
            int c = k0 + kn * 16 + lo;
#pragma unroll
            for (int i = 0; i < 4; i++) {
                int r = qw + hi * 4 + i;
                float a = s[kn][i] * scale + pad[kn];
                if (c > r) a = NEGC;
                float p = __expf(a) * invl[i];       // masked -> exactly 0
                Ph[(size_t)r * 1024 + c] = p;
                plds[w][hi * 4 + i][kn * 16 + lo] = (__bf16)p;
            }
        }
        __builtin_amdgcn_s_setprio(1);
#pragma unroll
        for (int ks = 0; ks < 2; ks++) {
            bf16x8 pf = *(const bf16x8*)(&plds[w][lo][ks * 32 + hi * 8]);
#pragma unroll
            for (int dt = 0; dt < 4; dt++) {
                bf16x8 vf = *(const bf16x8*)(&vt[cur][dt * 16 + lo][ks * 32 + hi * 8]);
                cacc[dt] = __builtin_amdgcn_mfma_f32_16x16x32_bf16(pf, vf, cacc[dt], 0, 0, 0);
            }
        }
        __builtin_amdgcn_s_setprio(0);
        if (kt < KTB) {
#pragma unroll
            for (int j = 0; j < 8; j++) vt[cur ^ 1][vcol + j][vrow] = va[j];
            if (kt + 1 < KTB)
                va = *(const bf16x8*)(Vh + (size_t)((kt + 2) * 64 + vrow) * 64 + vcol);
        }
        WAITL; BAR;
    }

    // ctx store (normalized already): [4096][768] bf16, col = h*64 + d
#pragma unroll
    for (int dt = 0; dt < 4; dt++) {
#pragma unroll
        for (int i = 0; i < 4; i++) {
            int m = b * 1024 + qw + hi * 4 + i;
            int n = h * 64 + dt * 16 + lo;
            ctx[(size_t)m * 768 + n] = (__bf16)cacc[dt][i];
        }
    }

    // zero tail beyond block-causal bound (cols >= q0+128)
    for (int c = (KTB + 1) * 64 + lo * 4; c < 1024; c += 64) {
#pragma unroll
        for (int i = 0; i < 4; i++) {
            f32x4 z = {};
            *(f32x4*)(Ph + (size_t)(qw + hi * 4 + i) * 1024 + c) = z;
        }
    }
#undef STAGE_K
#undef KFRAG
#undef WAITV
#undef WAITL
#undef BAR
}

// ---------------------------------------------------------------- layernorm (wave per row)
__global__ __launch_bounds__(256) void ln_kernel(
    const float* __restrict__ Y, const float* __restrict__ g, const float* __restrict__ bta,
    float* __restrict__ out)
{
    int row = blockIdx.x * 4 + (threadIdx.x >> 6);
    int l = threadIdx.x & 63;
    const float* yr = Y + (size_t)row * 768;
    f32x4 v0 = *(const f32x4*)(yr + l * 4);
    f32x4 v1 = *(const f32x4*)(yr + 256 + l * 4);
    f32x4 v2 = *(const f32x4*)(yr + 512 + l * 4);
    float s = v0[0] + v0[1] + v0[2] + v0[3] + v1[0] + v1[1] + v1[2] + v1[3]
            + v2[0] + v2[1] + v2[2] + v2[3];
#pragma unroll
    for (int m = 1; m < 64; m <<= 1) s += __shfl_xor(s, m);
    float mu = s * (1.0f / 768.0f);
    float ss = 0.0f;
#pragma unroll
    for (int j = 0; j < 4; j++) {
        float d0 = v0[j] - mu, d1 = v1[j] - mu, d2 = v2[j] - mu;
        ss += d0 * d0 + d1 * d1 + d2 * d2;
    }
#pragma unroll
    for (int m = 1; m < 64; m <<= 1) ss += __shfl_xor(ss, m);
    float r = rsqrtf(ss * (1.0f / 768.0f) + 1e-12f);
    float* orow = out + (size_t)row * 768;
#pragma unroll
    for (int c = 0; c < 3; c++) {
        f32x4 v = (c == 0) ? v0 : ((c == 1) ? v1 : v2);
        int col = c * 256 + l * 4;
        f32x4 gg = *(const f32x4*)(g + col);
        f32x4 bb = *(const f32x4*)(bta + col);
        f32x4 o;
#pragma unroll
        for (int j = 0; j < 4; j++) o[j] = (v[j] - mu) * r * gg[j] + bb[j];
        *(f32x4*)(orow + col) = o;
    }
}

// ---------------------------------------------------------------- launch
extern "C" void kernel_launch(void* const* d_in, const int* in_sizes, int n_in,
                              void* d_out, int out_size, void* d_ws, size_t ws_size,
                              hipStream_t stream)
{
    const float* emb   = (const float*)d_in[0];
    const float* pmask = (const float*)d_in[1];
    const float* wq = (const float*)d_in[2];  const float* bq = (const float*)d_in[3];
    const float* wk = (const float*)d_in[4];  const float* bk = (const float*)d_in[5];
    const float* wv = (const float*)d_in[6];  const float* bv = (const float*)d_in[7];
    const float* wo = (const float*)d_in[8];  const float* bo = (const float*)d_in[9];
    const float* lng = (const float*)d_in[10]; const float* lnb = (const float*)d_in[11];

    __bf16* Xb   = (__bf16*)d_ws;            // 4096*768
    __bf16* Wall = Xb + 4096 * 768;          // 4*768*768  [Wq|Wk|Wv|Wo]
    __bf16* Qb   = Wall + 4 * 589824;
    __bf16* Kb   = Qb + 3145728;
    __bf16* Vb   = Kb + 3145728;
    __bf16* Cb   = Vb + 3145728;
    float*  Yf   = (float*)(Cb + 3145728);   // 4096*768 f32

    float* normed = (float*)d_out;
    float* probs  = normed + (size_t)4096 * 768;

    cvt_all<<<2688, 256, 0, stream>>>(emb, wq, wk, wv, wo, Xb, Wall);

    gemm128<0><<<576, 256, 0, stream>>>(Xb, Wall, bq, bk, bv, Qb, Kb, Vb, nullptr, nullptr);
    attn_kernel<<<384, 512, 0, stream>>>(Qb, Kb, Vb, pmask, probs, Cb);
    gemm128<1><<<192, 256, 0, stream>>>(Cb, Wall + 3 * 589824, bo, nullptr, nullptr,
                                        nullptr, nullptr, nullptr, emb, Yf);
    ln_kernel<<<1024, 256, 0, stream>>>(Yf, lng, lnb, normed);
}

// Round 17
// 120.262 us; speedup vs baseline: 1.0458x; 1.0458x over previous
//
#include <hip/hip_runtime.h>
#include <hip/hip_bf16.h>

typedef __bf16 bf16x8 __attribute__((ext_vector_type(8)));
typedef float  f32x4  __attribute__((ext_vector_type(4)));

#define NEGC  (-10000.0f)
#define NEGL2 (-14426.950408889634f)   // -10000 * log2(e)

static __device__ __forceinline__ void glds16(const __bf16* src, __bf16* dst) {
    __builtin_amdgcn_global_load_lds((const __attribute__((address_space(1))) unsigned int*)src,
                                     (__attribute__((address_space(3))) unsigned int*)dst, 16, 0, 0);
}

// ---------------------------------------------------------------- fused f32->bf16 convert
__global__ __launch_bounds__(256) void cvt_all(
    const float* __restrict__ emb, const float* __restrict__ wq, const float* __restrict__ wk,
    const float* __restrict__ wv, const float* __restrict__ wo,
    __bf16* __restrict__ Xb, __bf16* __restrict__ Wall)
{
    int blk = blockIdx.x;
    const float* src; __bf16* dst; int i;
    if (blk < 1536) {
        src = emb; dst = Xb; i = blk * 256 + threadIdx.x;
    } else {
        int b2 = blk - 1536;
        int which = b2 / 288;
        src = which == 0 ? wq : which == 1 ? wk : which == 2 ? wv : wo;
        dst = Wall + (size_t)which * 589824;
        i = (b2 - which * 288) * 256 + threadIdx.x;
    }
    f32x4 a = *(const f32x4*)(src + (size_t)i * 8);
    f32x4 b = *(const f32x4*)(src + (size_t)i * 8 + 4);
    bf16x8 o;
    o[0] = (__bf16)a[0]; o[1] = (__bf16)a[1]; o[2] = (__bf16)a[2]; o[3] = (__bf16)a[3];
    o[4] = (__bf16)b[0]; o[5] = (__bf16)b[1]; o[6] = (__bf16)b[2]; o[7] = (__bf16)b[3];
    *(bf16x8*)(dst + (size_t)i * 8) = o;
}

// ---------------------------------------------------------------- GEMM (R14: BK=64 + XOR swizzle, XCD grid)
template<int MODE>
__global__ __launch_bounds__(256) void gemm128(
    const __bf16* __restrict__ A, const __bf16* __restrict__ Bw,
    const float* __restrict__ b0, const float* __restrict__ b1, const float* __restrict__ b2,
    __bf16* __restrict__ O0, __bf16* __restrict__ O1, __bf16* __restrict__ O2,
    const float* __restrict__ res, float* __restrict__ Yout)
{
    __shared__ __align__(16) __bf16 As[128 * 64];
    __shared__ __align__(16) __bf16 Bs[128 * 64];
    const int K = 768;
    const int NT = (MODE == 0) ? 18 : 6;
    int wgid = blockIdx.x;
    int xcd = wgid & 7;
    int t = wgid >> 3;
    int m0 = (xcd * 4 + t / NT) * 128;
    int n0 = (t % NT) * 128;

    int tid = threadIdx.x;
    int l = tid & 63, w = tid >> 6;
    int lo = l & 15, hi = l >> 4;
    int wr = w >> 1, wc = w & 1;

    f32x4 acc[4][4] = {};

    int srow = tid >> 3;
    int scb  = (tid & 7) ^ (srow & 7);
    const __bf16* gA = A + (size_t)(m0 + srow) * K + scb * 8;
    const __bf16* gB = Bw + (size_t)(n0 + srow) * K + scb * 8;
    __bf16* lA = As + tid * 8;
    __bf16* lB = Bs + tid * 8;

    for (int k0 = 0; k0 < K; k0 += 64) {
        if (k0) __syncthreads();
#pragma unroll
        for (int p = 0; p < 4; p++) {
            glds16(gA + (size_t)p * 32 * K + k0, lA + p * 2048);
            glds16(gB + (size_t)p * 32 * K + k0, lB + p * 2048);
        }
        __syncthreads();

#pragma unroll
        for (int kk = 0; kk < 2; kk++) {
            bf16x8 af[4], bfr[4];
#pragma unroll
            for (int mi = 0; mi < 4; mi++)
                af[mi] = *(const bf16x8*)(As + (wr * 64 + mi * 16 + lo) * 64 + (((kk * 4 + hi) ^ (lo & 7)) * 8));
#pragma unroll
            for (int ni = 0; ni < 4; ni++)
                bfr[ni] = *(const bf16x8*)(Bs + (wc * 64 + ni * 16 + lo) * 64 + (((kk * 4 + hi) ^ (lo & 7)) * 8));
#pragma unroll
            for (int mi = 0; mi < 4; mi++)
#pragma unroll
                for (int ni = 0; ni < 4; ni++)
                    acc[mi][ni] = __builtin_amdgcn_mfma_f32_16x16x32_bf16(af[mi], bfr[ni], acc[mi][ni], 0, 0, 0);
        }
    }

    if constexpr (MODE == 0) {
        int which = n0 / 768;
        const float* bias = which == 0 ? b0 : (which == 1 ? b1 : b2);
        __bf16* O = which == 0 ? O0 : (which == 1 ? O1 : O2);
        int nbase = n0 - which * 768;
#pragma unroll
        for (int mi = 0; mi < 4; mi++)
#pragma unroll
            for (int ni = 0; ni < 4; ni++) {
                int within = nbase + wc * 64 + ni * 16 + lo;
                float bv = bias[within];
                int h = within >> 6, d = within & 63;
#pragma unroll
                for (int i = 0; i < 4; i++) {
                    int m = m0 + wr * 64 + mi * 16 + hi * 4 + i;
                    int bb = m >> 10, s = m & 1023;
                    O[(size_t)((bb * 12 + h) * 1024 + s) * 64 + d] = (__bf16)(acc[mi][ni][i] + bv);
                }
            }
    } else {
#pragma unroll
        for (int mi = 0; mi < 4; mi++)
#pragma unroll
            for (int ni = 0; ni < 4; ni++) {
                int n = n0 + wc * 64 + ni * 16 + lo;
                float bv = b0[n];
#pragma unroll
                for (int i = 0; i < 4; i++) {
                    int m = m0 + wr * 64 + mi * 16 + hi * 4 + i;
                    size_t idx = (size_t)m * 768 + n;
                    Yout[idx] = acc[mi][ni][i] + bv + res[idx];
                }
            }
    }
}

// ---------------------------------------------------------------- attention (R15 exact + raw v_exp_f32)
// __expf (v_mul+v_exp) -> __builtin_amdgcn_exp2f (v_exp only) with log2e
// folded into scl2/NEGL2 at compile time. Masked lanes: 2^-14427 == 0 exactly.
// Everything else byte-identical to R15 (counted-vmcnt, XCD grid, QBLK=64).
__global__ __launch_bounds__(256) void attn_kernel(
    const __bf16* __restrict__ Q, const __bf16* __restrict__ K, const __bf16* __restrict__ V,
    const float* __restrict__ pmask, float* __restrict__ Pout, __bf16* __restrict__ ctx)
{
    int wgid = blockIdx.x;
    int xcd = wgid & 7;
    int t = wgid >> 3;              // 0..95
    int bh = xcd * 6 + (t % 6);     // 6 heads per XCD
    int y = t / 6;                  // 0..15
    int b = bh / 12, h = bh - b * 12;
    int q0 = y * 64;
    int tid = threadIdx.x, l = tid & 63, w = tid >> 6;
    int lo = l & 15, hi = l >> 4;
    int qw = q0 + w * 16;

    const __bf16* Qh = Q + (size_t)bh * 65536;
    const __bf16* Kh = K + (size_t)bh * 65536;
    const __bf16* Vh = V + (size_t)bh * 65536;
    float* Ph = Pout + (size_t)bh * 1048576;
    const float* pm = pmask + b * 1024;

    __shared__ __align__(16) __bf16 Ks[2][64][64];    // 16 KB, dbuf, XOR-swizzled cols
    __shared__ __align__(16) __bf16 vt[2][64][72];    // 18 KB, V^T [d][key], dbuf
    __shared__ __align__(16) __bf16 plds[4][16][72];  // 9 KB, per-wave P tile

    const float scl2 = 0.036084391824351615f * 1.4426950408889634f;  // log2e/sqrt(768)

    bf16x8 qf0 = *(const bf16x8*)(Qh + (size_t)(qw + lo) * 64 + hi * 8);
    bf16x8 qf1 = *(const bf16x8*)(Qh + (size_t)(qw + lo) * 64 + 32 + hi * 8);

    int srow = tid >> 3;
    int scb  = (tid & 7) ^ (srow & 7);
    __bf16* ldst0 = &Ks[0][0][0] + tid * 8;

#define STAGE_K(buf, kt)  do {                                             \
        glds16(Kh + (size_t)((kt) * 64 + srow) * 64 + scb * 8,             \
               ldst0 + (buf) * 4096);                                      \
        glds16(Kh + (size_t)((kt) * 64 + 32 + srow) * 64 + scb * 8,        \
               ldst0 + (buf) * 4096 + 2048);                               \
    } while (0)

#define KFRAG(buf, kn, dh) \
    (*(const bf16x8*)(&Ks[buf][(kn) * 16 + lo][(((dh) * 4 + hi) ^ (lo & 7)) * 8]))

#define WAITV(n)  asm volatile("s_waitcnt vmcnt(" #n ")" ::: "memory")
#define WAITL     asm volatile("s_waitcnt lgkmcnt(0)" ::: "memory")
#define BAR       __builtin_amdgcn_s_barrier()

    // ---------------- pass 1: row sums; counted-vmcnt phase sync
    float lsum[4] = {};
    STAGE_K(0, 0);
    for (int kt = 0; kt <= y; kt++) {
        int cur = kt & 1;
        if (kt < y) { STAGE_K(cur ^ 1, kt + 1); WAITV(2); }
        else        { WAITV(0); }
        BAR;
        int k0 = kt * 64;
        float pad[4];
#pragma unroll
        for (int kn = 0; kn < 4; kn++) pad[kn] = (1.0f - pm[k0 + kn * 16 + lo]) * NEGL2;
        f32x4 s[4] = {};
        __builtin_amdgcn_s_setprio(1);
#pragma unroll
        for (int kn = 0; kn < 4; kn++) {
            s[kn] = __builtin_amdgcn_mfma_f32_16x16x32_bf16(qf0, KFRAG(cur, kn, 0), s[kn], 0, 0, 0);
            s[kn] = __builtin_amdgcn_mfma_f32_16x16x32_bf16(qf1, KFRAG(cur, kn, 1), s[kn], 0, 0, 0);
        }
        __builtin_amdgcn_s_setprio(0);
#pragma unroll
        for (int kn = 0; kn < 4; kn++) {
            int c = k0 + kn * 16 + lo;
#pragma unroll
            for (int i = 0; i < 4; i++) {
                int r = qw + hi * 4 + i;
                float a = s[kn][i] * scl2 + pad[kn];
                if (c > r) a = NEGL2;
                lsum[i] += __builtin_amdgcn_exp2f(a);
            }
        }
        WAITL; BAR;
    }

    float invl[4];
#pragma unroll
    for (int i = 0; i < 4; i++) {
        float s = lsum[i];
        s += __shfl_xor(s, 1);
        s += __shfl_xor(s, 2);
        s += __shfl_xor(s, 4);
        s += __shfl_xor(s, 8);
        invl[i] = 1.0f / s;
    }

    // ---------------- pass 2: QK recompute, P store, PV; vmcnt(16) phase sync
    int vrow = tid >> 2, vcol = (tid & 3) * 16;
    bf16x8 va, vb;
    {   // prologue: K0 + V0 staged, V1 prefetched; one full drain
        STAGE_K(0, 0);
        const __bf16* vp = Vh + (size_t)vrow * 64 + vcol;
        va = *(const bf16x8*)vp; vb = *(const bf16x8*)(vp + 8);
#pragma unroll
        for (int j = 0; j < 8; j++) vt[0][vcol + j][vrow] = va[j];
#pragma unroll
        for (int j = 0; j < 8; j++) vt[0][vcol + 8 + j][vrow] = vb[j];
        if (y > 0) {
            const __bf16* vp1 = Vh + (size_t)(64 + vrow) * 64 + vcol;
            va = *(const bf16x8*)vp1; vb = *(const bf16x8*)(vp1 + 8);
        }
        __syncthreads();
    }

    f32x4 cacc[4] = {};
    for (int kt = 0; kt <= y; kt++) {
        int cur = kt & 1;
        if (kt < y) STAGE_K(cur ^ 1, kt + 1);
        WAITV(16);
        BAR;
        int k0 = kt * 64;
        float pad[4];
#pragma unroll
        for (int kn = 0; kn < 4; kn++) pad[kn] = (1.0f - pm[k0 + kn * 16 + lo]) * NEGL2;
        f32x4 s[4] = {};
        __builtin_amdgcn_s_setprio(1);
#pragma unroll
        for (int kn = 0; kn < 4; kn++) {
            s[kn] = __builtin_amdgcn_mfma_f32_16x16x32_bf16(qf0, KFRAG(cur, kn, 0), s[kn], 0, 0, 0);
            s[kn] = __builtin_amdgcn_mfma_f32_16x16x32_bf16(qf1, KFRAG(cur, kn, 1), s[kn], 0, 0, 0);
        }
        __builtin_amdgcn_s_setprio(0);
#pragma unroll
        for (int kn = 0; kn < 4; kn++) {
            int c = k0 + kn * 16 + lo;
#pragma unroll
            for (int i = 0; i < 4; i++) {
                int r = qw + hi * 4 + i;
                float a = s[kn][i] * scl2 + pad[kn];
                if (c > r) a = NEGL2;
                float p = __builtin_amdgcn_exp2f(a) * invl[i];   // masked -> exactly 0
                Ph[(size_t)r * 1024 + c] = p;
                plds[w][hi * 4 + i][kn * 16 + lo] = (__bf16)p;
            }
        }
        __builtin_amdgcn_s_setprio(1);
#pragma unroll
        for (int ks = 0; ks < 2; ks++) {
            bf16x8 pf = *(const bf16x8*)(&plds[w][lo][ks * 32 + hi * 8]);
#pragma unroll
            for (int dt = 0; dt < 4; dt++) {
                bf16x8 vf = *(const bf16x8*)(&vt[cur][dt * 16 + lo][ks * 32 + hi * 8]);
                cacc[dt] = __builtin_amdgcn_mfma_f32_16x16x32_bf16(pf, vf, cacc[dt], 0, 0, 0);
            }
        }
        __builtin_amdgcn_s_setprio(0);
        if (kt < y) {
#pragma unroll
            for (int j = 0; j < 8; j++) vt[cur ^ 1][vcol + j][vrow] = va[j];
#pragma unroll
            for (int j = 0; j < 8; j++) vt[cur ^ 1][vcol + 8 + j][vrow] = vb[j];
            if (kt + 1 < y) {
                const __bf16* vp = Vh + (size_t)((kt + 2) * 64 + vrow) * 64 + vcol;
                va = *(const bf16x8*)vp; vb = *(const bf16x8*)(vp + 8);
            }
        }
        WAITL; BAR;
    }

    // ctx store (normalized already): [4096][768] bf16, col = h*64 + d
#pragma unroll
    for (int dt = 0; dt < 4; dt++) {
#pragma unroll
        for (int i = 0; i < 4; i++) {
            int m = b * 1024 + qw + hi * 4 + i;
            int n = h * 64 + dt * 16 + lo;
            ctx[(size_t)m * 768 + n] = (__bf16)cacc[dt][i];
        }
    }

    // zero tail beyond block-causal bound
    for (int c = (y + 1) * 64 + lo * 4; c < 1024; c += 64) {
#pragma unroll
        for (int i = 0; i < 4; i++) {
            f32x4 z = {};
            *(f32x4*)(Ph + (size_t)(qw + hi * 4 + i) * 1024 + c) = z;
        }
    }
#undef STAGE_K
#undef KFRAG
#undef WAITV
#undef WAITL
#undef BAR
}

// ---------------------------------------------------------------- layernorm (wave per row)
__global__ __launch_bounds__(256) void ln_kernel(
    const float* __restrict__ Y, const float* __restrict__ g, const float* __restrict__ bta,
    float* __restrict__ out)
{
    int row = blockIdx.x * 4 + (threadIdx.x >> 6);
    int l = threadIdx.x & 63;
    const float* yr = Y + (size_t)row * 768;
    f32x4 v0 = *(const f32x4*)(yr + l * 4);
    f32x4 v1 = *(const f32x4*)(yr + 256 + l * 4);
    f32x4 v2 = *(const f32x4*)(yr + 512 + l * 4);
    float s = v0[0] + v0[1] + v0[2] + v0[3] + v1[0] + v1[1] + v1[2] + v1[3]
            + v2[0] + v2[1] + v2[2] + v2[3];
#pragma unroll
    for (int m = 1; m < 64; m <<= 1) s += __shfl_xor(s, m);
    float mu = s * (1.0f / 768.0f);
    float ss = 0.0f;
#pragma unroll
    for (int j = 0; j < 4; j++) {
        float d0 = v0[j] - mu, d1 = v1[j] - mu, d2 = v2[j] - mu;
        ss += d0 * d0 + d1 * d1 + d2 * d2;
    }
#pragma unroll
    for (int m = 1; m < 64; m <<= 1) ss += __shfl_xor(ss, m);
    float r = rsqrtf(ss * (1.0f / 768.0f) + 1e-12f);
    float* orow = out + (size_t)row * 768;
#pragma unroll
    for (int c = 0; c < 3; c++) {
        f32x4 v = (c == 0) ? v0 : ((c == 1) ? v1 : v2);
        int col = c * 256 + l * 4;
        f32x4 gg = *(const f32x4*)(g + col);
        f32x4 bb = *(const f32x4*)(bta + col);
        f32x4 o;
#pragma unroll
        for (int j = 0; j < 4; j++) o[j] = (v[j] - mu) * r * gg[j] + bb[j];
        *(f32x4*)(orow + col) = o;
    }
}

// ---------------------------------------------------------------- launch
extern "C" void kernel_launch(void* const* d_in, const int* in_sizes, int n_in,
                              void* d_out, int out_size, void* d_ws, size_t ws_size,
                              hipStream_t stream)
{
    const float* emb   = (const float*)d_in[0];
    const float* pmask = (const float*)d_in[1];
    const float* wq = (const float*)d_in[2];  const float* bq = (const float*)d_in[3];
    const float* wk = (const float*)d_in[4];  const float* bk = (const float*)d_in[5];
    const float* wv = (const float*)d_in[6];  const float* bv = (const float*)d_in[7];
    const float* wo = (const float*)d_in[8];  const float* bo = (const float*)d_in[9];
    const float* lng = (const float*)d_in[10]; const float* lnb = (const float*)d_in[11];

    __bf16* Xb   = (__bf16*)d_ws;            // 4096*768
    __bf16* Wall = Xb + 4096 * 768;          // 4*768*768  [Wq|Wk|Wv|Wo]
    __bf16* Qb   = Wall + 4 * 589824;
    __bf16* Kb   = Qb + 3145728;
    __bf16* Vb   = Kb + 3145728;
    __bf16* Cb   = Vb + 3145728;
    float*  Yf   = (float*)(Cb + 3145728);   // 4096*768 f32

    float* normed = (float*)d_out;
    float* probs  = normed + (size_t)4096 * 768;

    cvt_all<<<2688, 256, 0, stream>>>(emb, wq, wk, wv, wo, Xb, Wall);

    gemm128<0><<<576, 256, 0, stream>>>(Xb, Wall, bq, bk, bv, Qb, Kb, Vb, nullptr, nullptr);
    attn_kernel<<<768, 256, 0, stream>>>(Qb, Kb, Vb, pmask, probs, Cb);
    gemm128<1><<<192, 256, 0, stream>>>(Cb, Wall + 3 * 589824, bo, nullptr, nullptr,
                                        nullptr, nullptr, nullptr, emb, Yf);
    ln_kernel<<<1024, 256, 0, stream>>>(Yf, lng, lnb, normed);
}

// Round 18
// 117.748 us; speedup vs baseline: 1.0681x; 1.0213x over previous
//
#include <hip/hip_runtime.h>
#include <hip/hip_bf16.h>

typedef __bf16 bf16x8 __attribute__((ext_vector_type(8)));
typedef float  f32x4  __attribute__((ext_vector_type(4)));

#define NEGC (-10000.0f)

static __device__ __forceinline__ void glds16(const __bf16* src, __bf16* dst) {
    __builtin_amdgcn_global_load_lds((const __attribute__((address_space(1))) unsigned int*)src,
                                     (__attribute__((address_space(3))) unsigned int*)dst, 16, 0, 0);
}

// ---------------------------------------------------------------- fused f32->bf16 convert
__global__ __launch_bounds__(256) void cvt_all(
    const float* __restrict__ emb, const float* __restrict__ wq, const float* __restrict__ wk,
    const float* __restrict__ wv, const float* __restrict__ wo,
    __bf16* __restrict__ Xb, __bf16* __restrict__ Wall)
{
    int blk = blockIdx.x;
    const float* src; __bf16* dst; int i;
    if (blk < 1536) {
        src = emb; dst = Xb; i = blk * 256 + threadIdx.x;
    } else {
        int b2 = blk - 1536;
        int which = b2 / 288;
        src = which == 0 ? wq : which == 1 ? wk : which == 2 ? wv : wo;
        dst = Wall + (size_t)which * 589824;
        i = (b2 - which * 288) * 256 + threadIdx.x;
    }
    f32x4 a = *(const f32x4*)(src + (size_t)i * 8);
    f32x4 b = *(const f32x4*)(src + (size_t)i * 8 + 4);
    bf16x8 o;
    o[0] = (__bf16)a[0]; o[1] = (__bf16)a[1]; o[2] = (__bf16)a[2]; o[3] = (__bf16)a[3];
    o[4] = (__bf16)b[0]; o[5] = (__bf16)b[1]; o[6] = (__bf16)b[2]; o[7] = (__bf16)b[3];
    *(bf16x8*)(dst + (size_t)i * 8) = o;
}

// ---------------------------------------------------------------- GEMM (R14: BK=64 + XOR swizzle, XCD grid)
template<int MODE>
__global__ __launch_bounds__(256) void gemm128(
    const __bf16* __restrict__ A, const __bf16* __restrict__ Bw,
    const float* __restrict__ b0, const float* __restrict__ b1, const float* __restrict__ b2,
    __bf16* __restrict__ O0, __bf16* __restrict__ O1, __bf16* __restrict__ O2,
    const float* __restrict__ res, float* __restrict__ Yout)
{
    __shared__ __align__(16) __bf16 As[128 * 64];
    __shared__ __align__(16) __bf16 Bs[128 * 64];
    const int K = 768;
    const int NT = (MODE == 0) ? 18 : 6;
    int wgid = blockIdx.x;
    int xcd = wgid & 7;
    int t = wgid >> 3;
    int m0 = (xcd * 4 + t / NT) * 128;
    int n0 = (t % NT) * 128;

    int tid = threadIdx.x;
    int l = tid & 63, w = tid >> 6;
    int lo = l & 15, hi = l >> 4;
    int wr = w >> 1, wc = w & 1;

    f32x4 acc[4][4] = {};

    int srow = tid >> 3;
    int scb  = (tid & 7) ^ (srow & 7);
    const __bf16* gA = A + (size_t)(m0 + srow) * K + scb * 8;
    const __bf16* gB = Bw + (size_t)(n0 + srow) * K + scb * 8;
    __bf16* lA = As + tid * 8;
    __bf16* lB = Bs + tid * 8;

    for (int k0 = 0; k0 < K; k0 += 64) {
        if (k0) __syncthreads();
#pragma unroll
        for (int p = 0; p < 4; p++) {
            glds16(gA + (size_t)p * 32 * K + k0, lA + p * 2048);
            glds16(gB + (size_t)p * 32 * K + k0, lB + p * 2048);
        }
        __syncthreads();

#pragma unroll
        for (int kk = 0; kk < 2; kk++) {
            bf16x8 af[4], bfr[4];
#pragma unroll
            for (int mi = 0; mi < 4; mi++)
                af[mi] = *(const bf16x8*)(As + (wr * 64 + mi * 16 + lo) * 64 + (((kk * 4 + hi) ^ (lo & 7)) * 8));
#pragma unroll
            for (int ni = 0; ni < 4; ni++)
                bfr[ni] = *(const bf16x8*)(Bs + (wc * 64 + ni * 16 + lo) * 64 + (((kk * 4 + hi) ^ (lo & 7)) * 8));
#pragma unroll
            for (int mi = 0; mi < 4; mi++)
#pragma unroll
                for (int ni = 0; ni < 4; ni++)
                    acc[mi][ni] = __builtin_amdgcn_mfma_f32_16x16x32_bf16(af[mi], bfr[ni], acc[mi][ni], 0, 0, 0);
        }
    }

    if constexpr (MODE == 0) {
        int which = n0 / 768;
        const float* bias = which == 0 ? b0 : (which == 1 ? b1 : b2);
        __bf16* O = which == 0 ? O0 : (which == 1 ? O1 : O2);
        int nbase = n0 - which * 768;
#pragma unroll
        for (int mi = 0; mi < 4; mi++)
#pragma unroll
            for (int ni = 0; ni < 4; ni++) {
                int within = nbase + wc * 64 + ni * 16 + lo;
                float bv = bias[within];
                int h = within >> 6, d = within & 63;
#pragma unroll
                for (int i = 0; i < 4; i++) {
                    int m = m0 + wr * 64 + mi * 16 + hi * 4 + i;
                    int bb = m >> 10, s = m & 1023;
                    O[(size_t)((bb * 12 + h) * 1024 + s) * 64 + d] = (__bf16)(acc[mi][ni][i] + bv);
                }
            }
    } else {
#pragma unroll
        for (int mi = 0; mi < 4; mi++)
#pragma unroll
            for (int ni = 0; ni < 4; ni++) {
                int n = n0 + wc * 64 + ni * 16 + lo;
                float bv = b0[n];
#pragma unroll
                for (int i = 0; i < 4; i++) {
                    int m = m0 + wr * 64 + mi * 16 + hi * 4 + i;
                    size_t idx = (size_t)m * 768 + n;
                    Yout[idx] = acc[mi][ni][i] + bv + res[idx];
                }
            }
    }
}

// ---------------------------------------------------------------- attention (R15: best-known, 118.0 us)
// KVBLK=64, K staged via global_load_lds (dbuf, XOR-swizzled source), V^T dbuf
// reg-load-early/scatter-late. Pass 1: staged row sums. Pass 2: QK recompute,
// scalar P store + PV. Counted-vmcnt phase sync. XCD-partitioned 1D grid.
// __expf only (exp2f libcall AND __builtin_amdgcn_exp2f both refuted R10-R12/R17).
__global__ __launch_bounds__(256) void attn_kernel(
    const __bf16* __restrict__ Q, const __bf16* __restrict__ K, const __bf16* __restrict__ V,
    const float* __restrict__ pmask, float* __restrict__ Pout, __bf16* __restrict__ ctx)
{
    int wgid = blockIdx.x;
    int xcd = wgid & 7;
    int t = wgid >> 3;              // 0..95
    int bh = xcd * 6 + (t % 6);     // 6 heads per XCD
    int y = t / 6;                  // 0..15
    int b = bh / 12, h = bh - b * 12;
    int q0 = y * 64;
    int tid = threadIdx.x, l = tid & 63, w = tid >> 6;
    int lo = l & 15, hi = l >> 4;
    int qw = q0 + w * 16;

    const __bf16* Qh = Q + (size_t)bh * 65536;
    const __bf16* Kh = K + (size_t)bh * 65536;
    const __bf16* Vh = V + (size_t)bh * 65536;
    float* Ph = Pout + (size_t)bh * 1048576;
    const float* pm = pmask + b * 1024;

    __shared__ __align__(16) __bf16 Ks[2][64][64];    // 16 KB, dbuf, XOR-swizzled cols
    __shared__ __align__(16) __bf16 vt[2][64][72];    // 18 KB, V^T [d][key], dbuf
    __shared__ __align__(16) __bf16 plds[4][16][72];  // 9 KB, per-wave P tile

    const float scale = 0.036084391824351615f;  // 1/sqrt(768)

    bf16x8 qf0 = *(const bf16x8*)(Qh + (size_t)(qw + lo) * 64 + hi * 8);
    bf16x8 qf1 = *(const bf16x8*)(Qh + (size_t)(qw + lo) * 64 + 32 + hi * 8);

    int srow = tid >> 3;
    int scb  = (tid & 7) ^ (srow & 7);
    __bf16* ldst0 = &Ks[0][0][0] + tid * 8;

#define STAGE_K(buf, kt)  do {                                             \
        glds16(Kh + (size_t)((kt) * 64 + srow) * 64 + scb * 8,             \
               ldst0 + (buf) * 4096);                                      \
        glds16(Kh + (size_t)((kt) * 64 + 32 + srow) * 64 + scb * 8,        \
               ldst0 + (buf) * 4096 + 2048);                               \
    } while (0)

#define KFRAG(buf, kn, dh) \
    (*(const bf16x8*)(&Ks[buf][(kn) * 16 + lo][(((dh) * 4 + hi) ^ (lo & 7)) * 8]))

#define WAITV(n)  asm volatile("s_waitcnt vmcnt(" #n ")" ::: "memory")
#define WAITL     asm volatile("s_waitcnt lgkmcnt(0)" ::: "memory")
#define BAR       __builtin_amdgcn_s_barrier()

    // ---------------- pass 1: row sums; counted-vmcnt phase sync
    float lsum[4] = {};
    STAGE_K(0, 0);
    for (int kt = 0; kt <= y; kt++) {
        int cur = kt & 1;
        if (kt < y) { STAGE_K(cur ^ 1, kt + 1); WAITV(2); }
        else        { WAITV(0); }
        BAR;
        int k0 = kt * 64;
        float pad[4];
#pragma unroll
        for (int kn = 0; kn < 4; kn++) pad[kn] = (1.0f - pm[k0 + kn * 16 + lo]) * NEGC;
        f32x4 s[4] = {};
        __builtin_amdgcn_s_setprio(1);
#pragma unroll
        for (int kn = 0; kn < 4; kn++) {
            s[kn] = __builtin_amdgcn_mfma_f32_16x16x32_bf16(qf0, KFRAG(cur, kn, 0), s[kn], 0, 0, 0);
            s[kn] = __builtin_amdgcn_mfma_f32_16x16x32_bf16(qf1, KFRAG(cur, kn, 1), s[kn], 0, 0, 0);
        }
        __builtin_amdgcn_s_setprio(0);
#pragma unroll
        for (int kn = 0; kn < 4; kn++) {
            int c = k0 + kn * 16 + lo;
#pragma unroll
            for (int i = 0; i < 4; i++) {
                int r = qw + hi * 4 + i;
                float a = s[kn][i] * scale + pad[kn];
                if (c > r) a = NEGC;
                lsum[i] += __expf(a);
            }
        }
        WAITL; BAR;
    }

    float invl[4];
#pragma unroll
    for (int i = 0; i < 4; i++) {
        float s = lsum[i];
        s += __shfl_xor(s, 1);
        s += __shfl_xor(s, 2);
        s += __shfl_xor(s, 4);
        s += __shfl_xor(s, 8);
        invl[i] = 1.0f / s;
    }

    // ---------------- pass 2: QK recompute, P store, PV; vmcnt(16) phase sync
    int vrow = tid >> 2, vcol = (tid & 3) * 16;
    bf16x8 va, vb;
    {   // prologue: K0 + V0 staged, V1 prefetched; one full drain
        STAGE_K(0, 0);
        const __bf16* vp = Vh + (size_t)vrow * 64 + vcol;
        va = *(const bf16x8*)vp; vb = *(const bf16x8*)(vp + 8);
#pragma unroll
        for (int j = 0; j < 8; j++) vt[0][vcol + j][vrow] = va[j];
#pragma unroll
        for (int j = 0; j < 8; j++) vt[0][vcol + 8 + j][vrow] = vb[j];
        if (y > 0) {
            const __bf16* vp1 = Vh + (size_t)(64 + vrow) * 64 + vcol;
            va = *(const bf16x8*)vp1; vb = *(const bf16x8*)(vp1 + 8);
        }
        __syncthreads();
    }

    f32x4 cacc[4] = {};
    for (int kt = 0; kt <= y; kt++) {
        int cur = kt & 1;
        if (kt < y) STAGE_K(cur ^ 1, kt + 1);
        WAITV(16);
        BAR;
        int k0 = kt * 64;
        float pad[4];
#pragma unroll
        for (int kn = 0; kn < 4; kn++) pad[kn] = (1.0f - pm[k0 + kn * 16 + lo]) * NEGC;
        f32x4 s[4] = {};
        __builtin_amdgcn_s_setprio(1);
#pragma unroll
        for (int kn = 0; kn < 4; kn++) {
            s[kn] = __builtin_amdgcn_mfma_f32_16x16x32_bf16(qf0, KFRAG(cur, kn, 0), s[kn], 0, 0, 0);
            s[kn] = __builtin_amdgcn_mfma_f32_16x16x32_bf16(qf1, KFRAG(cur, kn, 1), s[kn], 0, 0, 0);
        }
        __builtin_amdgcn_s_setprio(0);
#pragma unroll
        for (int kn = 0; kn < 4; kn++) {
            int c = k0 + kn * 16 + lo;
#pragma unroll
            for (int i = 0; i < 4; i++) {
                int r = qw + hi * 4 + i;
                float a = s[kn][i] * scale + pad[kn];
                if (c > r) a = NEGC;
                float p = __expf(a) * invl[i];       // masked -> exactly 0
                Ph[(size_t)r * 1024 + c] = p;
                plds[w][hi * 4 + i][kn * 16 + lo] = (__bf16)p;
            }
        }
        __builtin_amdgcn_s_setprio(1);
#pragma unroll
        for (int ks = 0; ks < 2; ks++) {
            bf16x8 pf = *(const bf16x8*)(&plds[w][lo][ks * 32 + hi * 8]);
#pragma unroll
            for (int dt = 0; dt < 4; dt++) {
                bf16x8 vf = *(const bf16x8*)(&vt[cur][dt * 16 + lo][ks * 32 + hi * 8]);
                cacc[dt] = __builtin_amdgcn_mfma_f32_16x16x32_bf16(pf, vf, cacc[dt], 0, 0, 0);
            }
        }
        __builtin_amdgcn_s_setprio(0);
        if (kt < y) {
#pragma unroll
            for (int j = 0; j < 8; j++) vt[cur ^ 1][vcol + j][vrow] = va[j];
#pragma unroll
            for (int j = 0; j < 8; j++) vt[cur ^ 1][vcol + 8 + j][vrow] = vb[j];
            if (kt + 1 < y) {
                const __bf16* vp = Vh + (size_t)((kt + 2) * 64 + vrow) * 64 + vcol;
                va = *(const bf16x8*)vp; vb = *(const bf16x8*)(vp + 8);
            }
        }
        WAITL; BAR;
    }

    // ctx store (normalized already): [4096][768] bf16, col = h*64 + d
#pragma unroll
    for (int dt = 0; dt < 4; dt++) {
#pragma unroll
        for (int i = 0; i < 4; i++) {
            int m = b * 1024 + qw + hi * 4 + i;
            int n = h * 64 + dt * 16 + lo;
            ctx[(size_t)m * 768 + n] = (__bf16)cacc[dt][i];
        }
    }

    // zero tail beyond block-causal bound
    for (int c = (y + 1) * 64 + lo * 4; c < 1024; c += 64) {
#pragma unroll
        for (int i = 0; i < 4; i++) {
            f32x4 z = {};
            *(f32x4*)(Ph + (size_t)(qw + hi * 4 + i) * 1024 + c) = z;
        }
    }
#undef STAGE_K
#undef KFRAG
#undef WAITV
#undef WAITL
#undef BAR
}

// ---------------------------------------------------------------- layernorm (wave per row)
__global__ __launch_bounds__(256) void ln_kernel(
    const float* __restrict__ Y, const float* __restrict__ g, const float* __restrict__ bta,
    float* __restrict__ out)
{
    int row = blockIdx.x * 4 + (threadIdx.x >> 6);
    int l = threadIdx.x & 63;
    const float* yr = Y + (size_t)row * 768;
    f32x4 v0 = *(const f32x4*)(yr + l * 4);
    f32x4 v1 = *(const f32x4*)(yr + 256 + l * 4);
    f32x4 v2 = *(const f32x4*)(yr + 512 + l * 4);
    float s = v0[0] + v0[1] + v0[2] + v0[3] + v1[0] + v1[1] + v1[2] + v1[3]
            + v2[0] + v2[1] + v2[2] + v2[3];
#pragma unroll
    for (int m = 1; m < 64; m <<= 1) s += __shfl_xor(s, m);
    float mu = s * (1.0f / 768.0f);
    float ss = 0.0f;
#pragma unroll
    for (int j = 0; j < 4; j++) {
        float d0 = v0[j] - mu, d1 = v1[j] - mu, d2 = v2[j] - mu;
        ss += d0 * d0 + d1 * d1 + d2 * d2;
    }
#pragma unroll
    for (int m = 1; m < 64; m <<= 1) ss += __shfl_xor(ss, m);
    float r = rsqrtf(ss * (1.0f / 768.0f) + 1e-12f);
    float* orow = out + (size_t)row * 768;
#pragma unroll
    for (int c = 0; c < 3; c++) {
        f32x4 v = (c == 0) ? v0 : ((c == 1) ? v1 : v2);
        int col = c * 256 + l * 4;
        f32x4 gg = *(const f32x4*)(g + col);
        f32x4 bb = *(const f32x4*)(bta + col);
        f32x4 o;
#pragma unroll
        for (int j = 0; j < 4; j++) o[j] = (v[j] - mu) * r * gg[j] + bb[j];
        *(f32x4*)(orow + col) = o;
    }
}

// ---------------------------------------------------------------- launch
extern "C" void kernel_launch(void* const* d_in, const int* in_sizes, int n_in,
                              void* d_out, int out_size, void* d_ws, size_t ws_size,
                              hipStream_t stream)
{
    const float* emb   = (const float*)d_in[0];
    const float* pmask = (const float*)d_in[1];
    const float* wq = (const float*)d_in[2];  const float* bq = (const float*)d_in[3];
    const float* wk = (const float*)d_in[4];  const float* bk = (const float*)d_in[5];
    const float* wv = (const float*)d_in[6];  const float* bv = (const float*)d_in[7];
    const float* wo = (const float*)d_in[8];  const float* bo = (const float*)d_in[9];
    const float* lng = (const float*)d_in[10]; const float* lnb = (const float*)d_in[11];

    __bf16* Xb   = (__bf16*)d_ws;            // 4096*768
    __bf16* Wall = Xb + 4096 * 768;          // 4*768*768  [Wq|Wk|Wv|Wo]
    __bf16* Qb   = Wall + 4 * 589824;
    __bf16* Kb   = Qb + 3145728;
    __bf16* Vb   = Kb + 3145728;
    __bf16* Cb   = Vb + 3145728;
    float*  Yf   = (float*)(Cb + 3145728);   // 4096*768 f32

    float* normed = (float*)d_out;
    float* probs  = normed + (size_t)4096 * 768;

    cvt_all<<<2688, 256, 0, stream>>>(emb, wq, wk, wv, wo, Xb, Wall);

    gemm128<0><<<576, 256, 0, stream>>>(Xb, Wall, bq, bk, bv, Qb, Kb, Vb, nullptr, nullptr);
    attn_kernel<<<768, 256, 0, stream>>>(Qb, Kb, Vb, pmask, probs, Cb);
    gemm128<1><<<192, 256, 0, stream>>>(Cb, Wall + 3 * 589824, bo, nullptr, nullptr,
                                        nullptr, nullptr, nullptr, emb, Yf);
    ln_kernel<<<1024, 256, 0, stream>>>(Yf, lng, lnb, normed);
}

// Round 19
// 112.092 us; speedup vs baseline: 1.1220x; 1.0505x over previous
//
#include <hip/hip_runtime.h>
#include <hip/hip_bf16.h>

typedef __bf16 bf16x8 __attribute__((ext_vector_type(8)));
typedef float  f32x4  __attribute__((ext_vector_type(4)));

#define NEGC (-10000.0f)

static __device__ __forceinline__ void glds16(const __bf16* src, __bf16* dst) {
    __builtin_amdgcn_global_load_lds((const __attribute__((address_space(1))) unsigned int*)src,
                                     (__attribute__((address_space(3))) unsigned int*)dst, 16, 0, 0);
}

// ---------------------------------------------------------------- fused f32->bf16 convert
__global__ __launch_bounds__(256) void cvt_all(
    const float* __restrict__ emb, const float* __restrict__ wq, const float* __restrict__ wk,
    const float* __restrict__ wv, const float* __restrict__ wo,
    __bf16* __restrict__ Xb, __bf16* __restrict__ Wall)
{
    int blk = blockIdx.x;
    const float* src; __bf16* dst; int i;
    if (blk < 1536) {
        src = emb; dst = Xb; i = blk * 256 + threadIdx.x;
    } else {
        int b2 = blk - 1536;
        int which = b2 / 288;
        src = which == 0 ? wq : which == 1 ? wk : which == 2 ? wv : wo;
        dst = Wall + (size_t)which * 589824;
        i = (b2 - which * 288) * 256 + threadIdx.x;
    }
    f32x4 a = *(const f32x4*)(src + (size_t)i * 8);
    f32x4 b = *(const f32x4*)(src + (size_t)i * 8 + 4);
    bf16x8 o;
    o[0] = (__bf16)a[0]; o[1] = (__bf16)a[1]; o[2] = (__bf16)a[2]; o[3] = (__bf16)a[3];
    o[4] = (__bf16)b[0]; o[5] = (__bf16)b[1]; o[6] = (__bf16)b[2]; o[7] = (__bf16)b[3];
    *(bf16x8*)(dst + (size_t)i * 8) = o;
}

// ---------------------------------------------------------------- GEMM (R14: BK=64 + XOR swizzle, XCD grid)
template<int MODE>
__global__ __launch_bounds__(256) void gemm128(
    const __bf16* __restrict__ A, const __bf16* __restrict__ Bw,
    const float* __restrict__ b0, const float* __restrict__ b1, const float* __restrict__ b2,
    __bf16* __restrict__ O0, __bf16* __restrict__ O1, __bf16* __restrict__ O2,
    const float* __restrict__ res, float* __restrict__ Yout)
{
    __shared__ __align__(16) __bf16 As[128 * 64];
    __shared__ __align__(16) __bf16 Bs[128 * 64];
    const int K = 768;
    const int NT = (MODE == 0) ? 18 : 6;
    int wgid = blockIdx.x;
    int xcd = wgid & 7;
    int t = wgid >> 3;
    int m0 = (xcd * 4 + t / NT) * 128;
    int n0 = (t % NT) * 128;

    int tid = threadIdx.x;
    int l = tid & 63, w = tid >> 6;
    int lo = l & 15, hi = l >> 4;
    int wr = w >> 1, wc = w & 1;

    f32x4 acc[4][4] = {};

    int srow = tid >> 3;
    int scb  = (tid & 7) ^ (srow & 7);
    const __bf16* gA = A + (size_t)(m0 + srow) * K + scb * 8;
    const __bf16* gB = Bw + (size_t)(n0 + srow) * K + scb * 8;
    __bf16* lA = As + tid * 8;
    __bf16* lB = Bs + tid * 8;

    for (int k0 = 0; k0 < K; k0 += 64) {
        if (k0) __syncthreads();
#pragma unroll
        for (int p = 0; p < 4; p++) {
            glds16(gA + (size_t)p * 32 * K + k0, lA + p * 2048);
            glds16(gB + (size_t)p * 32 * K + k0, lB + p * 2048);
        }
        __syncthreads();

#pragma unroll
        for (int kk = 0; kk < 2; kk++) {
            bf16x8 af[4], bfr[4];
#pragma unroll
            for (int mi = 0; mi < 4; mi++)
                af[mi] = *(const bf16x8*)(As + (wr * 64 + mi * 16 + lo) * 64 + (((kk * 4 + hi) ^ (lo & 7)) * 8));
#pragma unroll
            for (int ni = 0; ni < 4; ni++)
                bfr[ni] = *(const bf16x8*)(Bs + (wc * 64 + ni * 16 + lo) * 64 + (((kk * 4 + hi) ^ (lo & 7)) * 8));
#pragma unroll
            for (int mi = 0; mi < 4; mi++)
#pragma unroll
                for (int ni = 0; ni < 4; ni++)
                    acc[mi][ni] = __builtin_amdgcn_mfma_f32_16x16x32_bf16(af[mi], bfr[ni], acc[mi][ni], 0, 0, 0);
        }
    }

    if constexpr (MODE == 0) {
        int which = n0 / 768;
        const float* bias = which == 0 ? b0 : (which == 1 ? b1 : b2);
        __bf16* O = which == 0 ? O0 : (which == 1 ? O1 : O2);
        int nbase = n0 - which * 768;
#pragma unroll
        for (int mi = 0; mi < 4; mi++)
#pragma unroll
            for (int ni = 0; ni < 4; ni++) {
                int within = nbase + wc * 64 + ni * 16 + lo;
                float bv = bias[within];
                int h = within >> 6, d = within & 63;
#pragma unroll
                for (int i = 0; i < 4; i++) {
                    int m = m0 + wr * 64 + mi * 16 + hi * 4 + i;
                    int bb = m >> 10, s = m & 1023;
                    O[(size_t)((bb * 12 + h) * 1024 + s) * 64 + d] = (__bf16)(acc[mi][ni][i] + bv);
                }
            }
    } else {
#pragma unroll
        for (int mi = 0; mi < 4; mi++)
#pragma unroll
            for (int ni = 0; ni < 4; ni++) {
                int n = n0 + wc * 64 + ni * 16 + lo;
                float bv = b0[n];
#pragma unroll
                for (int i = 0; i < 4; i++) {
                    int m = m0 + wr * 64 + mi * 16 + hi * 4 + i;
                    size_t idx = (size_t)m * 768 + n;
                    Yout[idx] = acc[mi][ni][i] + bv + res[idx];
                }
            }
    }
}

// ---------------------------------------------------------------- attention (R18 + snake-balanced CU assignment)
// In-order fill gives CU c of an XCD slots {c, c+32, c+64}; with y = t/6 that
// is 19..34.5 work-units per CU (1.35x makespan). Snake: weight-rank
// rho = {c, 95-c, 32+c} per round -> y = 15 - rho/6, head = rho%6 ->
// per-CU work 23..28. Bijective; head->XCD locality preserved. Rest = R18.
__global__ __launch_bounds__(256) void attn_kernel(
    const __bf16* __restrict__ Q, const __bf16* __restrict__ K, const __bf16* __restrict__ V,
    const float* __restrict__ pmask, float* __restrict__ Pout, __bf16* __restrict__ ctx)
{
    int wgid = blockIdx.x;
    int xcd = wgid & 7;
    int slot = wgid >> 3;           // 0..95 (in-order fill: CU = slot%32, round = slot/32)
    int c32 = slot & 31, round = slot >> 5;
    int rho = (round == 0) ? c32 : (round == 1) ? (95 - c32) : (32 + c32);
    int y = 15 - rho / 6;           // 0..15
    int bh = xcd * 6 + (rho % 6);   // 6 heads per XCD
    int b = bh / 12, h = bh - b * 12;
    int q0 = y * 64;
    int tid = threadIdx.x, l = tid & 63, w = tid >> 6;
    int lo = l & 15, hi = l >> 4;
    int qw = q0 + w * 16;

    const __bf16* Qh = Q + (size_t)bh * 65536;
    const __bf16* Kh = K + (size_t)bh * 65536;
    const __bf16* Vh = V + (size_t)bh * 65536;
    float* Ph = Pout + (size_t)bh * 1048576;
    const float* pm = pmask + b * 1024;

    __shared__ __align__(16) __bf16 Ks[2][64][64];    // 16 KB, dbuf, XOR-swizzled cols
    __shared__ __align__(16) __bf16 vt[2][64][72];    // 18 KB, V^T [d][key], dbuf
    __shared__ __align__(16) __bf16 plds[4][16][72];  // 9 KB, per-wave P tile

    const float scale = 0.036084391824351615f;  // 1/sqrt(768)

    bf16x8 qf0 = *(const bf16x8*)(Qh + (size_t)(qw + lo) * 64 + hi * 8);
    bf16x8 qf1 = *(const bf16x8*)(Qh + (size_t)(qw + lo) * 64 + 32 + hi * 8);

    int srow = tid >> 3;
    int scb  = (tid & 7) ^ (srow & 7);
    __bf16* ldst0 = &Ks[0][0][0] + tid * 8;

#define STAGE_K(buf, kt)  do {                                             \
        glds16(Kh + (size_t)((kt) * 64 + srow) * 64 + scb * 8,             \
               ldst0 + (buf) * 4096);                                      \
        glds16(Kh + (size_t)((kt) * 64 + 32 + srow) * 64 + scb * 8,        \
               ldst0 + (buf) * 4096 + 2048);                               \
    } while (0)

#define KFRAG(buf, kn, dh) \
    (*(const bf16x8*)(&Ks[buf][(kn) * 16 + lo][(((dh) * 4 + hi) ^ (lo & 7)) * 8]))

#define WAITV(n)  asm volatile("s_waitcnt vmcnt(" #n ")" ::: "memory")
#define WAITL     asm volatile("s_waitcnt lgkmcnt(0)" ::: "memory")
#define BAR       __builtin_amdgcn_s_barrier()

    // ---------------- pass 1: row sums; counted-vmcnt phase sync
    float lsum[4] = {};
    STAGE_K(0, 0);
    for (int kt = 0; kt <= y; kt++) {
        int cur = kt & 1;
        if (kt < y) { STAGE_K(cur ^ 1, kt + 1); WAITV(2); }
        else        { WAITV(0); }
        BAR;
        int k0 = kt * 64;
        float pad[4];
#pragma unroll
        for (int kn = 0; kn < 4; kn++) pad[kn] = (1.0f - pm[k0 + kn * 16 + lo]) * NEGC;
        f32x4 s[4] = {};
        __builtin_amdgcn_s_setprio(1);
#pragma unroll
        for (int kn = 0; kn < 4; kn++) {
            s[kn] = __builtin_amdgcn_mfma_f32_16x16x32_bf16(qf0, KFRAG(cur, kn, 0), s[kn], 0, 0, 0);
            s[kn] = __builtin_amdgcn_mfma_f32_16x16x32_bf16(qf1, KFRAG(cur, kn, 1), s[kn], 0, 0, 0);
        }
        __builtin_amdgcn_s_setprio(0);
#pragma unroll
        for (int kn = 0; kn < 4; kn++) {
            int c = k0 + kn * 16 + lo;
#pragma unroll
            for (int i = 0; i < 4; i++) {
                int r = qw + hi * 4 + i;
                float a = s[kn][i] * scale + pad[kn];
                if (c > r) a = NEGC;
                lsum[i] += __expf(a);
            }
        }
        WAITL; BAR;
    }

    float invl[4];
#pragma unroll
    for (int i = 0; i < 4; i++) {
        float s = lsum[i];
        s += __shfl_xor(s, 1);
        s += __shfl_xor(s, 2);
        s += __shfl_xor(s, 4);
        s += __shfl_xor(s, 8);
        invl[i] = 1.0f / s;
    }

    // ---------------- pass 2: QK recompute, P store, PV; vmcnt(16) phase sync
    int vrow = tid >> 2, vcol = (tid & 3) * 16;
    bf16x8 va, vb;
    {   // prologue: K0 + V0 staged, V1 prefetched; one full drain
        STAGE_K(0, 0);
        const __bf16* vp = Vh + (size_t)vrow * 64 + vcol;
        va = *(const bf16x8*)vp; vb = *(const bf16x8*)(vp + 8);
#pragma unroll
        for (int j = 0; j < 8; j++) vt[0][vcol + j][vrow] = va[j];
#pragma unroll
        for (int j = 0; j < 8; j++) vt[0][vcol + 8 + j][vrow] = vb[j];
        if (y > 0) {
            const __bf16* vp1 = Vh + (size_t)(64 + vrow) * 64 + vcol;
            va = *(const bf16x8*)vp1; vb = *(const bf16x8*)(vp1 + 8);
        }
        __syncthreads();
    }

    f32x4 cacc[4] = {};
    for (int kt = 0; kt <= y; kt++) {
        int cur = kt & 1;
        if (kt < y) STAGE_K(cur ^ 1, kt + 1);
        WAITV(16);
        BAR;
        int k0 = kt * 64;
        float pad[4];
#pragma unroll
        for (int kn = 0; kn < 4; kn++) pad[kn] = (1.0f - pm[k0 + kn * 16 + lo]) * NEGC;
        f32x4 s[4] = {};
        __builtin_amdgcn_s_setprio(1);
#pragma unroll
        for (int kn = 0; kn < 4; kn++) {
            s[kn] = __builtin_amdgcn_mfma_f32_16x16x32_bf16(qf0, KFRAG(cur, kn, 0), s[kn], 0, 0, 0);
            s[kn] = __builtin_amdgcn_mfma_f32_16x16x32_bf16(qf1, KFRAG(cur, kn, 1), s[kn], 0, 0, 0);
        }
        __builtin_amdgcn_s_setprio(0);
#pragma unroll
        for (int kn = 0; kn < 4; kn++) {
            int c = k0 + kn * 16 + lo;
#pragma unroll
            for (int i = 0; i < 4; i++) {
                int r = qw + hi * 4 + i;
                float a = s[kn][i] * scale + pad[kn];
                if (c > r) a = NEGC;
                float p = __expf(a) * invl[i];       // masked -> exactly 0
                Ph[(size_t)r * 1024 + c] = p;
                plds[w][hi * 4 + i][kn * 16 + lo] = (__bf16)p;
            }
        }
        __builtin_amdgcn_s_setprio(1);
#pragma unroll
        for (int ks = 0; ks < 2; ks++) {
            bf16x8 pf = *(const bf16x8*)(&plds[w][lo][ks * 32 + hi * 8]);
#pragma unroll
            for (int dt = 0; dt < 4; dt++) {
                bf16x8 vf = *(const bf16x8*)(&vt[cur][dt * 16 + lo][ks * 32 + hi * 8]);
                cacc[dt] = __builtin_amdgcn_mfma_f32_16x16x32_bf16(pf, vf, cacc[dt], 0, 0, 0);
            }
        }
        __builtin_amdgcn_s_setprio(0);
        if (kt < y) {
#pragma unroll
            for (int j = 0; j < 8; j++) vt[cur ^ 1][vcol + j][vrow] = va[j];
#pragma unroll
            for (int j = 0; j < 8; j++) vt[cur ^ 1][vcol + 8 + j][vrow] = vb[j];
            if (kt + 1 < y) {
                const __bf16* vp = Vh + (size_t)((kt + 2) * 64 + vrow) * 64 + vcol;
                va = *(const bf16x8*)vp; vb = *(const bf16x8*)(vp + 8);
            }
        }
        WAITL; BAR;
    }

    // ctx store (normalized already): [4096][768] bf16, col = h*64 + d
#pragma unroll
    for (int dt = 0; dt < 4; dt++) {
#pragma unroll
        for (int i = 0; i < 4; i++) {
            int m = b * 1024 + qw + hi * 4 + i;
            int n = h * 64 + dt * 16 + lo;
            ctx[(size_t)m * 768 + n] = (__bf16)cacc[dt][i];
        }
    }

    // zero tail beyond block-causal bound
    for (int c = (y + 1) * 64 + lo * 4; c < 1024; c += 64) {
#pragma unroll
        for (int i = 0; i < 4; i++) {
            f32x4 z = {};
            *(f32x4*)(Ph + (size_t)(qw + hi * 4 + i) * 1024 + c) = z;
        }
    }
#undef STAGE_K
#undef KFRAG
#undef WAITV
#undef WAITL
#undef BAR
}

// ---------------------------------------------------------------- layernorm (wave per row)
__global__ __launch_bounds__(256) void ln_kernel(
    const float* __restrict__ Y, const float* __restrict__ g, const float* __restrict__ bta,
    float* __restrict__ out)
{
    int row = blockIdx.x * 4 + (threadIdx.x >> 6);
    int l = threadIdx.x & 63;
    const float* yr = Y + (size_t)row * 768;
    f32x4 v0 = *(const f32x4*)(yr + l * 4);
    f32x4 v1 = *(const f32x4*)(yr + 256 + l * 4);
    f32x4 v2 = *(const f32x4*)(yr + 512 + l * 4);
    float s = v0[0] + v0[1] + v0[2] + v0[3] + v1[0] + v1[1] + v1[2] + v1[3]
            + v2[0] + v2[1] + v2[2] + v2[3];
#pragma unroll
    for (int m = 1; m < 64; m <<= 1) s += __shfl_xor(s, m);
    float mu = s * (1.0f / 768.0f);
    float ss = 0.0f;
#pragma unroll
    for (int j = 0; j < 4; j++) {
        float d0 = v0[j] - mu, d1 = v1[j] - mu, d2 = v2[j] - mu;
        ss += d0 * d0 + d1 * d1 + d2 * d2;
    }
#pragma unroll
    for (int m = 1; m < 64; m <<= 1) ss += __shfl_xor(ss, m);
    float r = rsqrtf(ss * (1.0f / 768.0f) + 1e-12f);
    float* orow = out + (size_t)row * 768;
#pragma unroll
    for (int c = 0; c < 3; c++) {
        f32x4 v = (c == 0) ? v0 : ((c == 1) ? v1 : v2);
        int col = c * 256 + l * 4;
        f32x4 gg = *(const f32x4*)(g + col);
        f32x4 bb = *(const f32x4*)(bta + col);
        f32x4 o;
#pragma unroll
        for (int j = 0; j < 4; j++) o[j] = (v[j] - mu) * r * gg[j] + bb[j];
        *(f32x4*)(orow + col) = o;
    }
}

// ---------------------------------------------------------------- launch
extern "C" void kernel_launch(void* const* d_in, const int* in_sizes, int n_in,
                              void* d_out, int out_size, void* d_ws, size_t ws_size,
                              hipStream_t stream)
{
    const float* emb   = (const float*)d_in[0];
    const float* pmask = (const float*)d_in[1];
    const float* wq = (const float*)d_in[2];  const float* bq = (const float*)d_in[3];
    const float* wk = (const float*)d_in[4];  const float* bk = (const float*)d_in[5];
    const float* wv = (const float*)d_in[6];  const float* bv = (const float*)d_in[7];
    const float* wo = (const float*)d_in[8];  const float* bo = (const float*)d_in[9];
    const float* lng = (const float*)d_in[10]; const float* lnb = (const float*)d_in[11];

    __bf16* Xb   = (__bf16*)d_ws;            // 4096*768
    __bf16* Wall = Xb + 4096 * 768;          // 4*768*768  [Wq|Wk|Wv|Wo]
    __bf16* Qb   = Wall + 4 * 589824;
    __bf16* Kb   = Qb + 3145728;
    __bf16* Vb   = Kb + 3145728;
    __bf16* Cb   = Vb + 3145728;
    float*  Yf   = (float*)(Cb + 3145728);   // 4096*768 f32

    float* normed = (float*)d_out;
    float* probs  = normed + (size_t)4096 * 768;

    cvt_all<<<2688, 256, 0, stream>>>(emb, wq, wk, wv, wo, Xb, Wall);

    gemm128<0><<<576, 256, 0, stream>>>(Xb, Wall, bq, bk, bv, Qb, Kb, Vb, nullptr, nullptr);
    attn_kernel<<<768, 256, 0, stream>>>(Qb, Kb, Vb, pmask, probs, Cb);
    gemm128<1><<<192, 256, 0, stream>>>(Cb, Wall + 3 * 589824, bo, nullptr, nullptr,
                                        nullptr, nullptr, nullptr, emb, Yf);
    ln_kernel<<<1024, 256, 0, stream>>>(Yf, lng, lnb, normed);
}